// Round 13
// baseline (159.788 us; speedup 1.0000x reference)
//
#include <hip/hip_runtime.h>

#define N_NODES 100000
#define N_EDGES 1600000
#define HIDDEN 64
#define NBKT 782          // buckets of 128 dst nodes (782*128 = 100096)
#define BKT_SHIFT 7
#define NT 391            // tiles of 4096 edges (391*4096 = 1601536)
#define TILE 4096
#define EMBF_BLKS 6250    // N_NODES*16/256

typedef __attribute__((ext_vector_type(8))) short short8v;   // 8 bf16 (4 VGPRs)
typedef __attribute__((ext_vector_type(4))) float f32x4;

__device__ __forceinline__ unsigned short f2bf(float f) {
    union { float f; unsigned u; } v; v.f = f;
    return (unsigned short)((v.u + 0x7FFFu + ((v.u >> 16) & 1u)) >> 16);  // RNE
}
__device__ __forceinline__ float bf2f(unsigned short h) {
    union { unsigned u; float f; } v; v.u = ((unsigned)h) << 16;
    return v.f;
}

// tmp entry: bits[24:18]=dlow(7b), bits[17:1]=src(17b), bit0=t.

// ---------------------------------------------------------------- K0: embbf[n] = bf16(emb[x[n]]); last block: Bbf[o*192+k] = bf16(B[k][o])
__global__ __launch_bounds__(256) void k_embf(const int* __restrict__ x, const float* __restrict__ emb,
                                              const float* __restrict__ W1, const float* __restrict__ root1,
                                              unsigned short* __restrict__ embbf,
                                              unsigned short* __restrict__ Bbf) {
    if (blockIdx.x == EMBF_BLKS) {
        for (int e = threadIdx.x; e < 192 * 64; e += 256) {
            int o = e / 192, k = e - o * 192;
            float v = (k < 128) ? W1[k * 64 + o] : root1[(k - 128) * 64 + o];
            Bbf[e] = f2bf(v);
        }
        return;
    }
    int gid = blockIdx.x * 256 + threadIdx.x;   // N_NODES*16 threads
    int n = gid >> 4, q = gid & 15;
    if (n >= N_NODES) return;
    int row = x[n];
    float4 v = *(const float4*)&emb[(long long)row * HIDDEN + q * 4];
    ushort4 p;
    p.x = f2bf(v.x); p.y = f2bf(v.y); p.z = f2bf(v.z); p.w = f2bf(v.w);
    *(ushort4*)&embbf[n * HIDDEN + q * 4] = p;
}

// ---------------------------------------------------------------- K1: tile histogram (read-only over edges)
__global__ __launch_bounds__(512) void k_hist(const int* __restrict__ ei,
                                              int* __restrict__ tilecnt) {
    __shared__ int hist[NBKT];
    int tile = blockIdx.x, tid = threadIdx.x;
    for (int i = tid; i < NBKT; i += 512) hist[i] = 0;
    __syncthreads();
    int e0 = tile * TILE;
    int e1 = e0 + TILE; if (e1 > N_EDGES) e1 = N_EDGES;
    for (int e = e0 + tid; e < e1; e += 512) {
        int d = ei[N_EDGES + e];
        atomicAdd(&hist[d >> BKT_SHIFT], 1);
    }
    __syncthreads();
    for (int i = tid; i < NBKT; i += 512) tilecnt[tile * NBKT + i] = hist[i];
}

// ---------------------------------------------------------------- K2a: per-bucket exclusive scan over tiles
__global__ __launch_bounds__(512) void k_scanA(int* __restrict__ tilecnt, int* __restrict__ btot) {
    __shared__ int sc[512];
    int b = blockIdx.x, tid = threadIdx.x;
    int v = (tid < NT) ? tilecnt[tid * NBKT + b] : 0;
    sc[tid] = v;
    __syncthreads();
    for (int off = 1; off < 512; off <<= 1) {
        int a = sc[tid];
        int p = (tid >= off) ? sc[tid - off] : 0;
        __syncthreads();
        sc[tid] = a + p;
        __syncthreads();
    }
    if (tid < NT) tilecnt[tid * NBKT + b] = sc[tid] - v;   // exclusive within bucket
    if (tid == 511) btot[b] = sc[511];
}

// ---------------------------------------------------------------- K2b: exclusive scan of bucket totals
__global__ __launch_bounds__(1024) void k_scanB(const int* __restrict__ btot, int* __restrict__ bbase) {
    __shared__ int sc[1024];
    int tid = threadIdx.x;
    int v = (tid < NBKT) ? btot[tid] : 0;
    sc[tid] = v;
    __syncthreads();
    for (int off = 1; off < 1024; off <<= 1) {
        int a = sc[tid];
        int p = (tid >= off) ? sc[tid - off] : 0;
        __syncthreads();
        sc[tid] = a + p;
        __syncthreads();
    }
    if (tid < NBKT) bbase[tid] = sc[tid] - v;
}

// ---------------------------------------------------------------- K3: placement into bucket-contiguous tmp (LDS cursors)
__global__ __launch_bounds__(512) void k_place(const int* __restrict__ ei,
                                               const int* __restrict__ ntype,
                                               const int* __restrict__ tilecnt,
                                               const int* __restrict__ bbase,
                                               unsigned* __restrict__ tmp) {
    __shared__ int cur[NBKT];
    int tile = blockIdx.x, tid = threadIdx.x;
    for (int i = tid; i < NBKT; i += 512) cur[i] = bbase[i] + tilecnt[tile * NBKT + i];
    __syncthreads();
    int e0 = tile * TILE;
    int e1 = e0 + TILE; if (e1 > N_EDGES) e1 = N_EDGES;
    for (int e = e0 + tid; e < e1; e += 512) {
        int s = ei[e], d = ei[N_EDGES + e];
        int t = (ntype[s] == ntype[d]) ? 1 : 0;
        unsigned entry = ((unsigned)(d & 127) << 18) | ((unsigned)s << 1) | (unsigned)t;
        int pos = atomicAdd(&cur[d >> BKT_SHIFT], 1);   // LDS fetch-add: block-local, cheap
        tmp[pos] = entry;
    }
}

// ---------------------------------------------------------------- K4: per-bucket counting sort -> per-node CSR + cnt + row_ptr
__global__ __launch_bounds__(256) void k_sort(const unsigned* __restrict__ tmp,
                                              const int* __restrict__ bbase,
                                              const int* __restrict__ btot,
                                              int* __restrict__ cnt, int* __restrict__ row_ptr,
                                              int* __restrict__ csr) {
    __shared__ int hist[256];   // [dlow*2 + t]
    __shared__ int psum[256];
    int b = blockIdx.x, tid = threadIdx.x;
    hist[tid] = 0;
    __syncthreads();
    int base = bbase[b], m = btot[b];

    // pass 1: histogram over 256 (node,rel) bins
    for (int i = tid; i < m; i += 256) {
        unsigned pe = tmp[base + i];
        atomicAdd(&hist[(int)((pe >> 17) & 0xFE) | (int)(pe & 1)], 1);  // (dlow<<1)|t
    }
    __syncthreads();

    // block scan (Hillis-Steele) over 256 bins
    int h = hist[tid];
    psum[tid] = h;
    __syncthreads();
    for (int off = 1; off < 256; off <<= 1) {
        int a = psum[tid];
        int p = (tid >= off) ? psum[tid - off] : 0;
        __syncthreads();
        psum[tid] = a + p;
        __syncthreads();
    }
    int excl = psum[tid] - h;

    int node = b * 128 + (tid >> 1);
    if (node < N_NODES) {
        cnt[node * 2 + (tid & 1)] = h;
        if ((tid & 1) == 0) row_ptr[node] = base + excl;
    }
    __syncthreads();
    hist[tid] = excl;   // becomes running placement cursor
    __syncthreads();

    // pass 2: placement (csr stores bare src; rel implied by position)
    for (int i = tid; i < m; i += 256) {
        unsigned pe = tmp[base + i];
        int bin = (int)((pe >> 17) & 0xFE) | (int)(pe & 1);
        int pos = base + atomicAdd(&hist[bin], 1);
        csr[pos] = (int)((pe >> 1) & 0x1FFFF);
    }
}

// ---------------------------------------------------------------- K5: bf16 gather-aggregate layer 1 (4 edges/wave, ushort4 lanes)
__global__ void k_gather1(const int* __restrict__ csr, const int* __restrict__ row_ptr,
                          const int* __restrict__ cnt, const unsigned short* __restrict__ embbf,
                          unsigned short* __restrict__ aggbf) {
    int gid = blockIdx.x * blockDim.x + threadIdx.x;
    int n = gid >> 6;
    int lane = gid & 63;
    if (n >= N_NODES) return;
    int q = lane >> 4;               // edge slot 0..3
    int ch = (lane & 15) * 4;        // channel quad
    int beg = row_ptr[n];
    int c0 = cnt[2 * n], c1 = cnt[2 * n + 1];
    int tot = c0 + c1;
    float a00 = 0.f, a01 = 0.f, a02 = 0.f, a03 = 0.f;
    float a10 = 0.f, a11 = 0.f, a12 = 0.f, a13 = 0.f;
    int jj = 0;
    for (; jj + 16 <= tot; jj += 16) {
        int j0 = jj + q, j1 = jj + 4 + q, j2 = jj + 8 + q, j3 = jj + 12 + q;
        int s0 = csr[beg + j0], s1 = csr[beg + j1], s2 = csr[beg + j2], s3 = csr[beg + j3];
        ushort4 v0 = *(const ushort4*)&embbf[s0 * HIDDEN + ch];
        ushort4 v1 = *(const ushort4*)&embbf[s1 * HIDDEN + ch];
        ushort4 v2 = *(const ushort4*)&embbf[s2 * HIDDEN + ch];
        ushort4 v3 = *(const ushort4*)&embbf[s3 * HIDDEN + ch];
        if (j0 < c0) { a00 += bf2f(v0.x); a01 += bf2f(v0.y); a02 += bf2f(v0.z); a03 += bf2f(v0.w); }
        else         { a10 += bf2f(v0.x); a11 += bf2f(v0.y); a12 += bf2f(v0.z); a13 += bf2f(v0.w); }
        if (j1 < c0) { a00 += bf2f(v1.x); a01 += bf2f(v1.y); a02 += bf2f(v1.z); a03 += bf2f(v1.w); }
        else         { a10 += bf2f(v1.x); a11 += bf2f(v1.y); a12 += bf2f(v1.z); a13 += bf2f(v1.w); }
        if (j2 < c0) { a00 += bf2f(v2.x); a01 += bf2f(v2.y); a02 += bf2f(v2.z); a03 += bf2f(v2.w); }
        else         { a10 += bf2f(v2.x); a11 += bf2f(v2.y); a12 += bf2f(v2.z); a13 += bf2f(v2.w); }
        if (j3 < c0) { a00 += bf2f(v3.x); a01 += bf2f(v3.y); a02 += bf2f(v3.z); a03 += bf2f(v3.w); }
        else         { a10 += bf2f(v3.x); a11 += bf2f(v3.y); a12 += bf2f(v3.z); a13 += bf2f(v3.w); }
    }
    for (int j = jj + q; j < tot; j += 4) {
        int s = csr[beg + j];
        ushort4 v = *(const ushort4*)&embbf[s * HIDDEN + ch];
        if (j < c0) { a00 += bf2f(v.x); a01 += bf2f(v.y); a02 += bf2f(v.z); a03 += bf2f(v.w); }
        else        { a10 += bf2f(v.x); a11 += bf2f(v.y); a12 += bf2f(v.z); a13 += bf2f(v.w); }
    }
    // reduce across the 4 quarter-groups (lanes q=0..3 hold partials for same channels)
    a00 += __shfl_xor(a00, 16); a00 += __shfl_xor(a00, 32);
    a01 += __shfl_xor(a01, 16); a01 += __shfl_xor(a01, 32);
    a02 += __shfl_xor(a02, 16); a02 += __shfl_xor(a02, 32);
    a03 += __shfl_xor(a03, 16); a03 += __shfl_xor(a03, 32);
    a10 += __shfl_xor(a10, 16); a10 += __shfl_xor(a10, 32);
    a11 += __shfl_xor(a11, 16); a11 += __shfl_xor(a11, 32);
    a12 += __shfl_xor(a12, 16); a12 += __shfl_xor(a12, 32);
    a13 += __shfl_xor(a13, 16); a13 += __shfl_xor(a13, 32);
    if (q == 0) {
        float n0 = 1.0f / (float)(c0 > 1 ? c0 : 1);
        float n1 = 1.0f / (float)(c1 > 1 ? c1 : 1);
        ushort4 w0, w1;
        w0.x = f2bf(a00 * n0); w0.y = f2bf(a01 * n0); w0.z = f2bf(a02 * n0); w0.w = f2bf(a03 * n0);
        w1.x = f2bf(a10 * n1); w1.y = f2bf(a11 * n1); w1.z = f2bf(a12 * n1); w1.w = f2bf(a13 * n1);
        *(ushort4*)&aggbf[n * 128 + ch] = w0;
        *(ushort4*)&aggbf[n * 128 + 64 + ch] = w1;
    }
}

// ---------------------------------------------------------------- K6: MFMA fused layer1 transform + relu + layer2 scalars
// LDS-free: A from global bf16 (aggbf k<128, embbf k>=128); B fragments from global Bbf (L2 broadcast).
__global__ __launch_bounds__(256) void k_l1mfma(const unsigned short* __restrict__ embbf,
                                                const unsigned short* __restrict__ aggbf,
                                                const unsigned short* __restrict__ Bbf,
                                                const float* __restrict__ b1,
                                                const float* __restrict__ W2, const float* __restrict__ root2,
                                                const float* __restrict__ b2,
                                                float* __restrict__ s, float* __restrict__ out) {
    int tid = threadIdx.x;
    int w = tid >> 6, lane = tid & 63;
    int nodeBase = blockIdx.x * 64;

    // --- MFMA: A lane layout row=lane&15, k=8*(lane>>4)+j; B: k same, col=lane&15
    int r = lane & 15, g = lane >> 4;
    int node = nodeBase + w * 16 + r;
    int cn = node < N_NODES ? node : 0;
    const unsigned short* arow = &aggbf[cn * 128];
    const unsigned short* erow = &embbf[cn * HIDDEN];
    f32x4 acc0 = {0.f, 0.f, 0.f, 0.f}, acc1 = acc0, acc2 = acc0, acc3 = acc0;
#pragma unroll
    for (int ks = 0; ks < 6; ++ks) {
        int koff = ks * 32 + g * 8;
        short8v av = (ks < 4) ? *(const short8v*)&arow[koff]
                              : *(const short8v*)&erow[koff - 128];
        short8v bv0 = *(const short8v*)&Bbf[r * 192 + koff];
        short8v bv1 = *(const short8v*)&Bbf[(16 + r) * 192 + koff];
        short8v bv2 = *(const short8v*)&Bbf[(32 + r) * 192 + koff];
        short8v bv3 = *(const short8v*)&Bbf[(48 + r) * 192 + koff];
        acc0 = __builtin_amdgcn_mfma_f32_16x16x32_bf16(av, bv0, acc0, 0, 0, 0);
        acc1 = __builtin_amdgcn_mfma_f32_16x16x32_bf16(av, bv1, acc1, 0, 0, 0);
        acc2 = __builtin_amdgcn_mfma_f32_16x16x32_bf16(av, bv2, acc2, 0, 0, 0);
        acc3 = __builtin_amdgcn_mfma_f32_16x16x32_bf16(av, bv3, acc3, 0, 0, 0);
    }

    // --- epilogue: C/D layout col=lane&15 (channel nt*16+r), row=(lane>>4)*4+reg (node)
    float b10 = b1[r], b11 = b1[16 + r], b12 = b1[32 + r], b13 = b1[48 + r];
    float w2a0 = W2[r], w2a1 = W2[16 + r], w2a2 = W2[32 + r], w2a3 = W2[48 + r];
    float w2b0 = W2[64 + r], w2b1 = W2[80 + r], w2b2 = W2[96 + r], w2b3 = W2[112 + r];
    float rr0 = root2[r], rr1 = root2[16 + r], rr2 = root2[32 + r], rr3 = root2[48 + r];
    float b2v = b2[0];
#pragma unroll
    for (int reg = 0; reg < 4; ++reg) {
        float h0 = acc0[reg] + b10; h0 = h0 > 0.f ? h0 : 0.f;
        float h1 = acc1[reg] + b11; h1 = h1 > 0.f ? h1 : 0.f;
        float h2 = acc2[reg] + b12; h2 = h2 > 0.f ? h2 : 0.f;
        float h3 = acc3[reg] + b13; h3 = h3 > 0.f ? h3 : 0.f;
        float p0 = h0 * w2a0 + h1 * w2a1 + h2 * w2a2 + h3 * w2a3;
        float p1 = h0 * w2b0 + h1 * w2b1 + h2 * w2b2 + h3 * w2b3;
        float p2 = h0 * rr0  + h1 * rr1  + h2 * rr2  + h3 * rr3;
#pragma unroll
        for (int mk = 8; mk >= 1; mk >>= 1) {
            p0 += __shfl_xor(p0, mk);
            p1 += __shfl_xor(p1, mk);
            p2 += __shfl_xor(p2, mk);
        }
        if (r == 0) {
            int nd = nodeBase + w * 16 + g * 4 + reg;
            if (nd < N_NODES) {
                s[nd] = p0;
                s[N_NODES + nd] = p1;
                out[nd] = p2 + b2v;
            }
        }
    }
}

// ---------------------------------------------------------------- K7: layer-2 edge aggregation (4 nodes/wave, 16 lanes each)
__global__ void k_gather2(const int* __restrict__ csr, const int* __restrict__ row_ptr,
                          const int* __restrict__ cnt, const float* __restrict__ sarr,
                          float* __restrict__ out) {
    int gid = blockIdx.x * blockDim.x + threadIdx.x;
    int n = gid >> 4;
    int l = gid & 15;
    if (n >= N_NODES) return;
    int beg = row_ptr[n];
    int c0 = cnt[2 * n], c1 = cnt[2 * n + 1];
    int tot = c0 + c1;
    float n0 = 1.0f / (float)(c0 > 1 ? c0 : 1);
    float n1 = 1.0f / (float)(c1 > 1 ? c1 : 1);
    float acc = 0.f;
    for (int j = l; j < tot; j += 16) {
        int src = csr[beg + j];
        acc += (j < c0) ? sarr[src] * n0 : sarr[N_NODES + src] * n1;
    }
    acc += __shfl_xor(acc, 1);
    acc += __shfl_xor(acc, 2);
    acc += __shfl_xor(acc, 4);
    acc += __shfl_xor(acc, 8);
    if (l == 0) out[n] += acc;
}

extern "C" void kernel_launch(void* const* d_in, const int* in_sizes, int n_in,
                              void* d_out, int out_size, void* d_ws, size_t ws_size,
                              hipStream_t stream) {
    const int* x      = (const int*)d_in[0];
    const int* ei     = (const int*)d_in[1];
    const int* ntype  = (const int*)d_in[2];
    const float* emb  = (const float*)d_in[3];
    const float* W1   = (const float*)d_in[4];
    const float* root1= (const float*)d_in[5];
    const float* b1   = (const float*)d_in[6];
    const float* W2   = (const float*)d_in[7];
    const float* root2= (const float*)d_in[8];
    const float* b2   = (const float*)d_in[9];
    float* out = (float*)d_out;

    char* ws = (char*)d_ws;
    size_t off = 0;
    auto alloc = [&](size_t bytes) -> void* {
        void* p = ws + off;
        off = (off + bytes + 255) & ~(size_t)255;
        return p;
    };
    int* tilecnt           = (int*)alloc((size_t)NT * NBKT * sizeof(int));
    int* btot              = (int*)alloc((size_t)NBKT * sizeof(int));
    int* bbase             = (int*)alloc((size_t)NBKT * sizeof(int));
    unsigned* tmp          = (unsigned*)alloc((size_t)N_EDGES * sizeof(unsigned));
    int* cnt               = (int*)alloc((size_t)N_NODES * 2 * sizeof(int));
    int* row_ptr           = (int*)alloc((size_t)N_NODES * sizeof(int));
    int* csr               = (int*)alloc((size_t)N_EDGES * sizeof(int));
    unsigned short* embbf  = (unsigned short*)alloc((size_t)N_NODES * HIDDEN * sizeof(unsigned short));
    unsigned short* aggbf  = (unsigned short*)alloc((size_t)N_NODES * 128 * sizeof(unsigned short));
    unsigned short* Bbf    = (unsigned short*)alloc((size_t)192 * 64 * sizeof(unsigned short));
    float* s               = (float*)alloc((size_t)N_NODES * 2 * sizeof(float));

    k_embf <<<EMBF_BLKS + 1, 256, 0, stream>>>(x, emb, W1, root1, embbf, Bbf);
    k_hist <<<NT, 512, 0, stream>>>(ei, tilecnt);
    k_scanA<<<NBKT, 512, 0, stream>>>(tilecnt, btot);
    k_scanB<<<1, 1024, 0, stream>>>(btot, bbase);
    k_place<<<NT, 512, 0, stream>>>(ei, ntype, tilecnt, bbase, tmp);
    k_sort <<<NBKT, 256, 0, stream>>>(tmp, bbase, btot, cnt, row_ptr, csr);
    k_gather1<<<(N_NODES * 64) / 256, 256, 0, stream>>>(csr, row_ptr, cnt, embbf, aggbf);
    k_l1mfma<<<(N_NODES + 63) / 64, 256, 0, stream>>>(embbf, aggbf, Bbf, b1,
                                                      W2, root2, b2, s, out);
    k_gather2<<<(N_NODES * 16 + 255) / 256, 256, 0, stream>>>(csr, row_ptr, cnt, s, out);
}

// Round 14
// 145.156 us; speedup vs baseline: 1.1008x; 1.1008x over previous
//
#include <hip/hip_runtime.h>

#define N_NODES 100000
#define N_EDGES 1600000
#define HIDDEN 64
#define NBKT 782          // buckets of 128 dst nodes (782*128 = 100096)
#define BKT_SHIFT 7
#define NT 391            // tiles of 4096 edges (391*4096 = 1601536)
#define TILE 4096

typedef __attribute__((ext_vector_type(8))) short short8v;   // 8 bf16 (4 VGPRs)
typedef __attribute__((ext_vector_type(4))) float f32x4;

__device__ __forceinline__ unsigned short f2bf(float f) {
    union { float f; unsigned u; } v; v.f = f;
    return (unsigned short)((v.u + 0x7FFFu + ((v.u >> 16) & 1u)) >> 16);  // RNE
}
__device__ __forceinline__ float bf2f(unsigned short h) {
    union { unsigned u; float f; } v; v.u = ((unsigned)h) << 16;
    return v.f;
}

// tmp entry: bits[24:18]=dlow(7b), bits[17:1]=src(17b), bit0=t.

// ---------------------------------------------------------------- K0: pre-gathered bf16 node features: embbf[n] = bf16(emb[x[n]])
__global__ __launch_bounds__(256) void k_embf(const int* __restrict__ x, const float* __restrict__ emb,
                                              unsigned short* __restrict__ embbf) {
    int gid = blockIdx.x * 256 + threadIdx.x;   // N_NODES*16 threads
    int n = gid >> 4, q = gid & 15;
    if (n >= N_NODES) return;
    int row = x[n];
    float4 v = *(const float4*)&emb[(long long)row * HIDDEN + q * 4];
    ushort4 p;
    p.x = f2bf(v.x); p.y = f2bf(v.y); p.z = f2bf(v.z); p.w = f2bf(v.w);
    *(ushort4*)&embbf[n * HIDDEN + q * 4] = p;
}

// ---------------------------------------------------------------- K1: tile histogram (read-only over edges)
__global__ __launch_bounds__(512) void k_hist(const int* __restrict__ ei,
                                              int* __restrict__ tilecnt) {
    __shared__ int hist[NBKT];
    int tile = blockIdx.x, tid = threadIdx.x;
    for (int i = tid; i < NBKT; i += 512) hist[i] = 0;
    __syncthreads();
    int e0 = tile * TILE;
    int e1 = e0 + TILE; if (e1 > N_EDGES) e1 = N_EDGES;
    for (int e = e0 + tid; e < e1; e += 512) {
        int d = ei[N_EDGES + e];
        atomicAdd(&hist[d >> BKT_SHIFT], 1);
    }
    __syncthreads();
    for (int i = tid; i < NBKT; i += 512) tilecnt[tile * NBKT + i] = hist[i];
}

// ---------------------------------------------------------------- K2a: per-bucket exclusive scan over tiles
__global__ __launch_bounds__(512) void k_scanA(int* __restrict__ tilecnt, int* __restrict__ btot) {
    __shared__ int sc[512];
    int b = blockIdx.x, tid = threadIdx.x;
    int v = (tid < NT) ? tilecnt[tid * NBKT + b] : 0;
    sc[tid] = v;
    __syncthreads();
    for (int off = 1; off < 512; off <<= 1) {
        int a = sc[tid];
        int p = (tid >= off) ? sc[tid - off] : 0;
        __syncthreads();
        sc[tid] = a + p;
        __syncthreads();
    }
    if (tid < NT) tilecnt[tid * NBKT + b] = sc[tid] - v;   // exclusive within bucket
    if (tid == 511) btot[b] = sc[511];
}

// ---------------------------------------------------------------- K2b: exclusive scan of bucket totals
__global__ __launch_bounds__(1024) void k_scanB(const int* __restrict__ btot, int* __restrict__ bbase) {
    __shared__ int sc[1024];
    int tid = threadIdx.x;
    int v = (tid < NBKT) ? btot[tid] : 0;
    sc[tid] = v;
    __syncthreads();
    for (int off = 1; off < 1024; off <<= 1) {
        int a = sc[tid];
        int p = (tid >= off) ? sc[tid - off] : 0;
        __syncthreads();
        sc[tid] = a + p;
        __syncthreads();
    }
    if (tid < NBKT) bbase[tid] = sc[tid] - v;
}

// ---------------------------------------------------------------- K3: placement into bucket-contiguous tmp (LDS cursors)
// recomputes t from ntype (no ps buffer)
__global__ __launch_bounds__(512) void k_place(const int* __restrict__ ei,
                                               const int* __restrict__ ntype,
                                               const int* __restrict__ tilecnt,
                                               const int* __restrict__ bbase,
                                               unsigned* __restrict__ tmp) {
    __shared__ int cur[NBKT];
    int tile = blockIdx.x, tid = threadIdx.x;
    for (int i = tid; i < NBKT; i += 512) cur[i] = bbase[i] + tilecnt[tile * NBKT + i];
    __syncthreads();
    int e0 = tile * TILE;
    int e1 = e0 + TILE; if (e1 > N_EDGES) e1 = N_EDGES;
    for (int e = e0 + tid; e < e1; e += 512) {
        int s = ei[e], d = ei[N_EDGES + e];
        int t = (ntype[s] == ntype[d]) ? 1 : 0;
        unsigned entry = ((unsigned)(d & 127) << 18) | ((unsigned)s << 1) | (unsigned)t;
        int pos = atomicAdd(&cur[d >> BKT_SHIFT], 1);   // LDS fetch-add: block-local, cheap
        tmp[pos] = entry;
    }
}

// ---------------------------------------------------------------- K4: per-bucket counting sort -> per-node CSR + cnt + row_ptr
__global__ __launch_bounds__(256) void k_sort(const unsigned* __restrict__ tmp,
                                              const int* __restrict__ bbase,
                                              const int* __restrict__ btot,
                                              int* __restrict__ cnt, int* __restrict__ row_ptr,
                                              int* __restrict__ csr) {
    __shared__ int hist[256];   // [dlow*2 + t]
    __shared__ int psum[256];
    int b = blockIdx.x, tid = threadIdx.x;
    hist[tid] = 0;
    __syncthreads();
    int base = bbase[b], m = btot[b];

    // pass 1: histogram over 256 (node,rel) bins
    for (int i = tid; i < m; i += 256) {
        unsigned pe = tmp[base + i];
        atomicAdd(&hist[(int)((pe >> 17) & 0xFE) | (int)(pe & 1)], 1);  // (dlow<<1)|t
    }
    __syncthreads();

    // block scan (Hillis-Steele) over 256 bins
    int h = hist[tid];
    psum[tid] = h;
    __syncthreads();
    for (int off = 1; off < 256; off <<= 1) {
        int a = psum[tid];
        int p = (tid >= off) ? psum[tid - off] : 0;
        __syncthreads();
        psum[tid] = a + p;
        __syncthreads();
    }
    int excl = psum[tid] - h;

    int node = b * 128 + (tid >> 1);
    if (node < N_NODES) {
        cnt[node * 2 + (tid & 1)] = h;
        if ((tid & 1) == 0) row_ptr[node] = base + excl;
    }
    __syncthreads();
    hist[tid] = excl;   // becomes running placement cursor
    __syncthreads();

    // pass 2: placement (csr stores bare src; rel implied by position)
    for (int i = tid; i < m; i += 256) {
        unsigned pe = tmp[base + i];
        int bin = (int)((pe >> 17) & 0xFE) | (int)(pe & 1);
        int pos = base + atomicAdd(&hist[bin], 1);
        csr[pos] = (int)((pe >> 1) & 0x1FFFF);
    }
}

// ---------------------------------------------------------------- K5: bf16 gather-aggregate layer 1 (4 edges/wave, ushort4 lanes)
__global__ void k_gather1(const int* __restrict__ csr, const int* __restrict__ row_ptr,
                          const int* __restrict__ cnt, const unsigned short* __restrict__ embbf,
                          unsigned short* __restrict__ aggbf) {
    int gid = blockIdx.x * blockDim.x + threadIdx.x;
    int n = gid >> 6;
    int lane = gid & 63;
    if (n >= N_NODES) return;
    int q = lane >> 4;               // edge slot 0..3
    int ch = (lane & 15) * 4;        // channel quad
    int beg = row_ptr[n];
    int c0 = cnt[2 * n], c1 = cnt[2 * n + 1];
    int tot = c0 + c1;
    float a00 = 0.f, a01 = 0.f, a02 = 0.f, a03 = 0.f;
    float a10 = 0.f, a11 = 0.f, a12 = 0.f, a13 = 0.f;
    int jj = 0;
    for (; jj + 16 <= tot; jj += 16) {
        int j0 = jj + q, j1 = jj + 4 + q, j2 = jj + 8 + q, j3 = jj + 12 + q;
        int s0 = csr[beg + j0], s1 = csr[beg + j1], s2 = csr[beg + j2], s3 = csr[beg + j3];
        ushort4 v0 = *(const ushort4*)&embbf[s0 * HIDDEN + ch];
        ushort4 v1 = *(const ushort4*)&embbf[s1 * HIDDEN + ch];
        ushort4 v2 = *(const ushort4*)&embbf[s2 * HIDDEN + ch];
        ushort4 v3 = *(const ushort4*)&embbf[s3 * HIDDEN + ch];
        if (j0 < c0) { a00 += bf2f(v0.x); a01 += bf2f(v0.y); a02 += bf2f(v0.z); a03 += bf2f(v0.w); }
        else         { a10 += bf2f(v0.x); a11 += bf2f(v0.y); a12 += bf2f(v0.z); a13 += bf2f(v0.w); }
        if (j1 < c0) { a00 += bf2f(v1.x); a01 += bf2f(v1.y); a02 += bf2f(v1.z); a03 += bf2f(v1.w); }
        else         { a10 += bf2f(v1.x); a11 += bf2f(v1.y); a12 += bf2f(v1.z); a13 += bf2f(v1.w); }
        if (j2 < c0) { a00 += bf2f(v2.x); a01 += bf2f(v2.y); a02 += bf2f(v2.z); a03 += bf2f(v2.w); }
        else         { a10 += bf2f(v2.x); a11 += bf2f(v2.y); a12 += bf2f(v2.z); a13 += bf2f(v2.w); }
        if (j3 < c0) { a00 += bf2f(v3.x); a01 += bf2f(v3.y); a02 += bf2f(v3.z); a03 += bf2f(v3.w); }
        else         { a10 += bf2f(v3.x); a11 += bf2f(v3.y); a12 += bf2f(v3.z); a13 += bf2f(v3.w); }
    }
    for (int j = jj + q; j < tot; j += 4) {
        int s = csr[beg + j];
        ushort4 v = *(const ushort4*)&embbf[s * HIDDEN + ch];
        if (j < c0) { a00 += bf2f(v.x); a01 += bf2f(v.y); a02 += bf2f(v.z); a03 += bf2f(v.w); }
        else        { a10 += bf2f(v.x); a11 += bf2f(v.y); a12 += bf2f(v.z); a13 += bf2f(v.w); }
    }
    // reduce across the 4 quarter-groups (lanes q=0..3 hold partials for same channels)
    a00 += __shfl_xor(a00, 16); a00 += __shfl_xor(a00, 32);
    a01 += __shfl_xor(a01, 16); a01 += __shfl_xor(a01, 32);
    a02 += __shfl_xor(a02, 16); a02 += __shfl_xor(a02, 32);
    a03 += __shfl_xor(a03, 16); a03 += __shfl_xor(a03, 32);
    a10 += __shfl_xor(a10, 16); a10 += __shfl_xor(a10, 32);
    a11 += __shfl_xor(a11, 16); a11 += __shfl_xor(a11, 32);
    a12 += __shfl_xor(a12, 16); a12 += __shfl_xor(a12, 32);
    a13 += __shfl_xor(a13, 16); a13 += __shfl_xor(a13, 32);
    if (q == 0) {
        float n0 = 1.0f / (float)(c0 > 1 ? c0 : 1);
        float n1 = 1.0f / (float)(c1 > 1 ? c1 : 1);
        ushort4 w0, w1;
        w0.x = f2bf(a00 * n0); w0.y = f2bf(a01 * n0); w0.z = f2bf(a02 * n0); w0.w = f2bf(a03 * n0);
        w1.x = f2bf(a10 * n1); w1.y = f2bf(a11 * n1); w1.z = f2bf(a12 * n1); w1.w = f2bf(a13 * n1);
        *(ushort4*)&aggbf[n * 128 + ch] = w0;
        *(ushort4*)&aggbf[n * 128 + 64 + ch] = w1;
    }
}

// ---------------------------------------------------------------- K6: MFMA fused layer1 transform + relu + layer2 scalars
// 256 thr = 4 waves; wave handles 16 nodes (M=16), K=192, N=64 via 6 K-steps x 4 N-tiles.
// A loaded DIRECTLY from global bf16 (aggbf k<128, embbf k>=128); B staged transposed in LDS.
#define KPAD 200
__global__ __launch_bounds__(256) void k_l1mfma(const unsigned short* __restrict__ embbf,
                                                const unsigned short* __restrict__ aggbf,
                                                const float* __restrict__ W1, const float* __restrict__ root1,
                                                const float* __restrict__ b1,
                                                const float* __restrict__ W2, const float* __restrict__ root2,
                                                const float* __restrict__ b2,
                                                float* __restrict__ s, float* __restrict__ out) {
    __shared__ unsigned short Bw[64][KPAD];      // 25.6 KB, Bw[o][k] = B[k][o]
    int tid = threadIdx.x;
    int w = tid >> 6, lane = tid & 63;
    int nodeBase = blockIdx.x * 64;

    // --- stage B (weights), whole block: 192x64 floats -> bf16 transposed
    for (int it = 0; it < 12; ++it) {
        int f = it * 256 + tid;          // 0..3071
        int k = f >> 4, o4 = (f & 15) * 4;
        float4 wv = (k < 128) ? *(const float4*)&W1[k * 64 + o4]
                              : *(const float4*)&root1[(k - 128) * 64 + o4];
        Bw[o4 + 0][k] = f2bf(wv.x);
        Bw[o4 + 1][k] = f2bf(wv.y);
        Bw[o4 + 2][k] = f2bf(wv.z);
        Bw[o4 + 3][k] = f2bf(wv.w);
    }
    __syncthreads();

    // --- MFMA: A lane layout row=lane&15, k=8*(lane>>4)+j; B: k same, col=lane&15
    int r = lane & 15, g = lane >> 4;
    int node = nodeBase + w * 16 + r;
    int cn = node < N_NODES ? node : 0;
    const unsigned short* arow = &aggbf[cn * 128];
    const unsigned short* erow = &embbf[cn * HIDDEN];
    f32x4 acc0 = {0.f, 0.f, 0.f, 0.f}, acc1 = acc0, acc2 = acc0, acc3 = acc0;
#pragma unroll
    for (int ks = 0; ks < 6; ++ks) {
        int koff = ks * 32 + g * 8;
        short8v av = (ks < 4) ? *(const short8v*)&arow[koff]
                              : *(const short8v*)&erow[koff - 128];
        short8v bv0 = *(const short8v*)&Bw[r][koff];
        short8v bv1 = *(const short8v*)&Bw[16 + r][koff];
        short8v bv2 = *(const short8v*)&Bw[32 + r][koff];
        short8v bv3 = *(const short8v*)&Bw[48 + r][koff];
        acc0 = __builtin_amdgcn_mfma_f32_16x16x32_bf16(av, bv0, acc0, 0, 0, 0);
        acc1 = __builtin_amdgcn_mfma_f32_16x16x32_bf16(av, bv1, acc1, 0, 0, 0);
        acc2 = __builtin_amdgcn_mfma_f32_16x16x32_bf16(av, bv2, acc2, 0, 0, 0);
        acc3 = __builtin_amdgcn_mfma_f32_16x16x32_bf16(av, bv3, acc3, 0, 0, 0);
    }

    // --- epilogue: C/D layout col=lane&15 (channel nt*16+r), row=(lane>>4)*4+reg (node)
    float b10 = b1[r], b11 = b1[16 + r], b12 = b1[32 + r], b13 = b1[48 + r];
    float w2a0 = W2[r], w2a1 = W2[16 + r], w2a2 = W2[32 + r], w2a3 = W2[48 + r];
    float w2b0 = W2[64 + r], w2b1 = W2[80 + r], w2b2 = W2[96 + r], w2b3 = W2[112 + r];
    float rr0 = root2[r], rr1 = root2[16 + r], rr2 = root2[32 + r], rr3 = root2[48 + r];
    float b2v = b2[0];
#pragma unroll
    for (int reg = 0; reg < 4; ++reg) {
        float h0 = acc0[reg] + b10; h0 = h0 > 0.f ? h0 : 0.f;
        float h1 = acc1[reg] + b11; h1 = h1 > 0.f ? h1 : 0.f;
        float h2 = acc2[reg] + b12; h2 = h2 > 0.f ? h2 : 0.f;
        float h3 = acc3[reg] + b13; h3 = h3 > 0.f ? h3 : 0.f;
        float p0 = h0 * w2a0 + h1 * w2a1 + h2 * w2a2 + h3 * w2a3;
        float p1 = h0 * w2b0 + h1 * w2b1 + h2 * w2b2 + h3 * w2b3;
        float p2 = h0 * rr0  + h1 * rr1  + h2 * rr2  + h3 * rr3;
#pragma unroll
        for (int mk = 8; mk >= 1; mk >>= 1) {
            p0 += __shfl_xor(p0, mk);
            p1 += __shfl_xor(p1, mk);
            p2 += __shfl_xor(p2, mk);
        }
        if (r == 0) {
            int nd = nodeBase + w * 16 + g * 4 + reg;
            if (nd < N_NODES) {
                s[nd] = p0;
                s[N_NODES + nd] = p1;
                out[nd] = p2 + b2v;
            }
        }
    }
}

// ---------------------------------------------------------------- K7: layer-2 edge aggregation (4 nodes/wave, 16 lanes each)
__global__ void k_gather2(const int* __restrict__ csr, const int* __restrict__ row_ptr,
                          const int* __restrict__ cnt, const float* __restrict__ sarr,
                          float* __restrict__ out) {
    int gid = blockIdx.x * blockDim.x + threadIdx.x;
    int n = gid >> 4;
    int l = gid & 15;
    if (n >= N_NODES) return;
    int beg = row_ptr[n];
    int c0 = cnt[2 * n], c1 = cnt[2 * n + 1];
    int tot = c0 + c1;
    float n0 = 1.0f / (float)(c0 > 1 ? c0 : 1);
    float n1 = 1.0f / (float)(c1 > 1 ? c1 : 1);
    float acc = 0.f;
    for (int j = l; j < tot; j += 16) {
        int src = csr[beg + j];
        acc += (j < c0) ? sarr[src] * n0 : sarr[N_NODES + src] * n1;
    }
    acc += __shfl_xor(acc, 1);
    acc += __shfl_xor(acc, 2);
    acc += __shfl_xor(acc, 4);
    acc += __shfl_xor(acc, 8);
    if (l == 0) out[n] += acc;
}

extern "C" void kernel_launch(void* const* d_in, const int* in_sizes, int n_in,
                              void* d_out, int out_size, void* d_ws, size_t ws_size,
                              hipStream_t stream) {
    const int* x      = (const int*)d_in[0];
    const int* ei     = (const int*)d_in[1];
    const int* ntype  = (const int*)d_in[2];
    const float* emb  = (const float*)d_in[3];
    const float* W1   = (const float*)d_in[4];
    const float* root1= (const float*)d_in[5];
    const float* b1   = (const float*)d_in[6];
    const float* W2   = (const float*)d_in[7];
    const float* root2= (const float*)d_in[8];
    const float* b2   = (const float*)d_in[9];
    float* out = (float*)d_out;

    char* ws = (char*)d_ws;
    size_t off = 0;
    auto alloc = [&](size_t bytes) -> void* {
        void* p = ws + off;
        off = (off + bytes + 255) & ~(size_t)255;
        return p;
    };
    int* tilecnt           = (int*)alloc((size_t)NT * NBKT * sizeof(int));
    int* btot              = (int*)alloc((size_t)NBKT * sizeof(int));
    int* bbase             = (int*)alloc((size_t)NBKT * sizeof(int));
    unsigned* tmp          = (unsigned*)alloc((size_t)N_EDGES * sizeof(unsigned));
    int* cnt               = (int*)alloc((size_t)N_NODES * 2 * sizeof(int));
    int* row_ptr           = (int*)alloc((size_t)N_NODES * sizeof(int));
    int* csr               = (int*)alloc((size_t)N_EDGES * sizeof(int));
    unsigned short* embbf  = (unsigned short*)alloc((size_t)N_NODES * HIDDEN * sizeof(unsigned short));
    unsigned short* aggbf  = (unsigned short*)alloc((size_t)N_NODES * 128 * sizeof(unsigned short));
    float* s               = (float*)alloc((size_t)N_NODES * 2 * sizeof(float));

    k_embf <<<(N_NODES * 16 + 255) / 256, 256, 0, stream>>>(x, emb, embbf);
    k_hist <<<NT, 512, 0, stream>>>(ei, tilecnt);
    k_scanA<<<NBKT, 512, 0, stream>>>(tilecnt, btot);
    k_scanB<<<1, 1024, 0, stream>>>(btot, bbase);
    k_place<<<NT, 512, 0, stream>>>(ei, ntype, tilecnt, bbase, tmp);
    k_sort <<<NBKT, 256, 0, stream>>>(tmp, bbase, btot, cnt, row_ptr, csr);
    k_gather1<<<(N_NODES * 64) / 256, 256, 0, stream>>>(csr, row_ptr, cnt, embbf, aggbf);
    k_l1mfma<<<(N_NODES + 63) / 64, 256, 0, stream>>>(embbf, aggbf, W1, root1, b1,
                                                      W2, root2, b2, s, out);
    k_gather2<<<(N_NODES * 16 + 255) / 256, 256, 0, stream>>>(csr, row_ptr, cnt, s, out);
}